// Round 16
// baseline (1095.122 us; speedup 1.0000x reference)
//
#include <hip/hip_runtime.h>
#include <math.h>

#define N_MEM 100
#define C_DIM 768
#define HW_SZ 2304            // 48*48
#define TEMP 0.07f
#define EPS_F 1e-8f
#define LAM_F 0.01f           // 1/N_MEM
#define NORM_EPS 1e-12f

#define NS   4                // n-split stripes (fixed)
#define SW   25               // stripe width (N_MEM/NS)
#define SWP  28               // mbuf padded stripe (unchanged)
#define CROW (NS * SWP)       // 112 floats per c in mbuf
#define SP2  32               // mTs padded stripe: 128B-aligned stripes [R16]
#define CROW2 (NS * SP2)      // 128 floats per c in mTs
#define ROWS 64               // rows per block
#define SCP  101              // LDS row pad: lane*101%32=lane*5 -> 2-way max
#define ZB   8                // scores c-loop batch
#define CB_R 8                // recon c-tile per stage per wave

typedef float f32x2  __attribute__((ext_vector_type(2)));
typedef float f32x4  __attribute__((ext_vector_type(4)));
typedef float f32x8  __attribute__((ext_vector_type(8)));
typedef float f32x16 __attribute__((ext_vector_type(16)));

// -------------------------------------------------------------------------
// Kernel 1: L2-normalize memory rows, store PADDED-TRANSPOSED:
// mTs[c][ns][SP2] with 128B-aligned stripes -> wave-uniform stripe reads
// merge into s_load_dwordx16/x8 (the 112B layout forced 7x dwordx4).
// Same value bits as every prior round (same reduction).
// -------------------------------------------------------------------------
__global__ __launch_bounds__(64) void prep_mT(const float* __restrict__ mem,
                                              float* __restrict__ mTs) {
#pragma clang fp contract(off)
    const int n = blockIdx.x;        // 0..99
    const int lane = threadIdx.x;    // 0..63
    const float* row = mem + n * C_DIM;

    float ss = 0.f;
    for (int c = lane; c < C_DIM; c += 64) {
        float v = row[c];
        ss = fmaf(v, v, ss);
    }
    for (int off = 32; off > 0; off >>= 1)
        ss += __shfl_down(ss, off);
    float norm = sqrtf(__shfl(ss, 0));
    float inv = 1.0f / fmaxf(norm, NORM_EPS);

    const int nsI = n / SW, j = n % SW;
    for (int c = lane; c < C_DIM; c += 64)
        mTs[(size_t)c * CROW2 + nsI * SP2 + j] = row[c] * inv;
}

// -------------------------------------------------------------------------
// FUSED kernel: scores -> softmax -> shrinkage -> w_hat -> reconstruction.
//
// R16 change (layout only): m stripe loads are f32x16 + f32x8 + scalar
// from the 128B-aligned mTs rows -> 3 SMEM insts/c instead of 7. Same
// values, same chain order -> bit-identical (absmax exactly 0.004943848
// in every passing round; threshold 5.27e-3). Softmax + recon compute
// byte-identical to R13/R15; mbuf staging re-indexed for mTs but writes
// the same mbuf layout.
// LDS: sc 25856B + mbuf 14336B = 40192B -> 4 blocks/CU.
// -------------------------------------------------------------------------
__global__ __launch_bounds__(256) void memmod_fused(const float* __restrict__ F,
                                                    const float* __restrict__ mTs,
                                                    float* __restrict__ Fhat,
                                                    float* __restrict__ What) {
#pragma clang fp contract(off)
    __shared__ float sc[ROWS][SCP];              // scores, then w_hat
    __shared__ float mbuf[NS * CB_R * CROW];     // recon m chunk

    const int tid  = threadIdx.x;
    const int lane = tid & 63;
    const int ws   = tid >> 6;
    const int wsu  = __builtin_amdgcn_readfirstlane(ws);   // force SGPR addr
    const int blk  = blockIdx.x;                 // 0..2303
    const int b    = blk / 36;                   // 36 blocks per image
    const int hw   = (blk % 36) * 64 + lane;     // 0..2303
    const int rowg = b * HW_SZ + hw;             // global row id
    const size_t plane = (size_t)b * C_DIM * HW_SZ + hw;

    f32x2 acc2[12];                              // chains j=0..23, paired
    float acc24 = 0.f;                           // chain j=24
#pragma unroll
    for (int p = 0; p < 12; ++p) acc2[p] = f32x2{0.f, 0.f};
    float ss = 0.f;

    // ---- scores: batched z loads, sequential-c PK-FMA chains, wide s_load m ----
    const float* Fp = F + plane;
    for (int c0 = 0; c0 < C_DIM; c0 += ZB) {
        float zb[ZB];                            // static indices -> VGPRs
#pragma unroll
        for (int u = 0; u < ZB; ++u)
            zb[u] = Fp[(size_t)(c0 + u) * HW_SZ];    // 8 coalesced loads in flight
#pragma unroll
        for (int u = 0; u < ZB; ++u) {
            const float zc = zb[u];
            ss = fmaf(zc, zc, ss);
            const float* mch = mTs + (size_t)(c0 + u) * CROW2 + wsu * SP2;  // uniform
            // 128B-aligned stripe: one x16, one x8, one dword (3 SMEM insts)
            const f32x16 M = *reinterpret_cast<const f32x16*>(mch);
            const f32x8  N = *reinterpret_cast<const f32x8*>(mch + 16);
            const float m24 = mch[24];

            f32x2 zz; zz.x = zc; zz.y = zc;
            acc2[0]  = __builtin_elementwise_fma(zz, __builtin_shufflevector(M, M, 0, 1),   acc2[0]);
            acc2[1]  = __builtin_elementwise_fma(zz, __builtin_shufflevector(M, M, 2, 3),   acc2[1]);
            acc2[2]  = __builtin_elementwise_fma(zz, __builtin_shufflevector(M, M, 4, 5),   acc2[2]);
            acc2[3]  = __builtin_elementwise_fma(zz, __builtin_shufflevector(M, M, 6, 7),   acc2[3]);
            acc2[4]  = __builtin_elementwise_fma(zz, __builtin_shufflevector(M, M, 8, 9),   acc2[4]);
            acc2[5]  = __builtin_elementwise_fma(zz, __builtin_shufflevector(M, M, 10, 11), acc2[5]);
            acc2[6]  = __builtin_elementwise_fma(zz, __builtin_shufflevector(M, M, 12, 13), acc2[6]);
            acc2[7]  = __builtin_elementwise_fma(zz, __builtin_shufflevector(M, M, 14, 15), acc2[7]);
            acc2[8]  = __builtin_elementwise_fma(zz, __builtin_shufflevector(N, N, 0, 1),   acc2[8]);
            acc2[9]  = __builtin_elementwise_fma(zz, __builtin_shufflevector(N, N, 2, 3),   acc2[9]);
            acc2[10] = __builtin_elementwise_fma(zz, __builtin_shufflevector(N, N, 4, 5),   acc2[10]);
            acc2[11] = __builtin_elementwise_fma(zz, __builtin_shufflevector(N, N, 6, 7),   acc2[11]);
            acc24 = fmaf(zc, m24, acc24);
        }
    }

    // ---- unpack to the acc[] layout (bit-identical values) ----
    float acc[SW];
#pragma unroll
    for (int p = 0; p < 12; ++p) { acc[2 * p] = acc2[p].x; acc[2 * p + 1] = acc2[p].y; }
    acc[24] = acc24;

    // ---- stage scores to LDS (read-only during softmax scans) ----
#pragma unroll
    for (int j = 0; j < SW; ++j)
        sc[lane][wsu * SW + j] = acc[j];
    __syncthreads();

    // ---- softmax + shrinkage: R1's exact op sequence, n = 0..99 ----
    const float scale = 1.0f / (fmaxf(sqrtf(ss), NORM_EPS) * TEMP);
    float mx = -INFINITY;
    for (int n = 0; n < N_MEM; ++n)
        mx = fmaxf(mx, sc[lane][n] * scale);
    float sum = 0.f;
    for (int n = 0; n < N_MEM; ++n)
        sum += expf(sc[lane][n] * scale - mx);
    float s2 = 0.f;
    for (int n = 0; n < N_MEM; ++n) {
        const float e = expf(sc[lane][n] * scale - mx);   // same bits as pass 2
        const float w = e / sum;
        const float d = w - LAM_F;
        s2 += (d > 0.f ? d : 0.f) * w / (fabsf(d) + EPS_F);
    }
    const float s2c = fmaxf(s2, EPS_F);

    // ---- all waves done reading scores; overwrite sc with w_hat ----
    __syncthreads();

    // own stripe: recompute wh from registers (same bits), emit to HBM + LDS
    float* wout = What + (size_t)rowg * N_MEM + wsu * SW;
#pragma unroll
    for (int j = 0; j < SW; ++j) {
        const float e = expf(acc[j] * scale - mx);
        const float w = e / sum;
        const float d = w - LAM_F;
        const float wh = (d > 0.f ? d : 0.f) * w / (fabsf(d) + EPS_F);
        const float whn = wh / s2c;
        wout[j] = whn;                           // output w_hat_spatial
        sc[lane][wsu * SW + j] = whn;            // recon operand (same bits)
    }

    // ---- reconstruction: Fhat[b][c][hw] = sum_n wh[row][n]*m[n][c] ----
    float* Fo = Fhat + plane;
    const int c0w = wsu * (C_DIM / NS);          // 192-wide c-stripe

    for (int cb = 0; cb < C_DIM / NS; cb += CB_R) {
        __syncthreads();                         // wh visible / prior chunk consumed
        {   // stage 4 c-regions x CB_R c's x 4 stripes x 28 floats (mbuf layout
            // unchanged; source re-indexed for mTs's 128-float rows)
            float4* dst4 = reinterpret_cast<float4*>(mbuf);
            for (int i = tid; i < NS * CB_R * CROW / 4; i += 256) {   // 896
                const int s   = i / (CB_R * CROW / 4);    // c-region (wave)
                const int rem = i % (CB_R * CROW / 4);    // 0..223
                const int t   = rem / (CROW / 4);         // c within tile
                const int q2  = rem % (CROW / 4);         // 0..27
                const int ns_ = q2 / 7;                   // stripe
                const int q   = q2 % 7;                   // float4 within stripe
                const int c   = s * (C_DIM / NS) + cb + t;
                dst4[i] = *reinterpret_cast<const float4*>(
                    mTs + (size_t)c * CROW2 + ns_ * SP2 + q * 4);
            }
        }
        __syncthreads();

        f32x2 v2[CB_R];                          // even/odd-j partial chains
        float vs[CB_R];                          // j=24 chain
#pragma unroll
        for (int t = 0; t < CB_R; ++t) { v2[t] = f32x2{0.f, 0.f}; vs[t] = 0.f; }

#pragma unroll
        for (int nc = 0; nc < NS; ++nc) {
            f32x2 wr2[12];
#pragma unroll
            for (int p = 0; p < 12; ++p)
                wr2[p] = f32x2{sc[lane][nc * SW + 2 * p],
                               sc[lane][nc * SW + 2 * p + 1]};   // 2-way max
            const float wr24 = sc[lane][nc * SW + 24];
#pragma unroll
            for (int t = 0; t < CB_R; ++t) {
                const float* mch = mbuf + (wsu * CB_R + t) * CROW + nc * SWP;
                const f32x4* mch4 = reinterpret_cast<const f32x4*>(mch);  // broadcast
#pragma unroll
                for (int q = 0; q < 6; ++q) {
                    const f32x4 m4 = mch4[q];
                    const f32x2 mlo = __builtin_shufflevector(m4, m4, 0, 1);
                    const f32x2 mhi = __builtin_shufflevector(m4, m4, 2, 3);
                    v2[t] = __builtin_elementwise_fma(wr2[2 * q], mlo, v2[t]);
                    v2[t] = __builtin_elementwise_fma(wr2[2 * q + 1], mhi, v2[t]);
                }
                vs[t] = fmaf(wr24, mch[24], vs[t]);
            }
        }
#pragma unroll
        for (int t = 0; t < CB_R; ++t)
            Fo[(size_t)(c0w + cb + t) * HW_SZ] = (v2[t].x + v2[t].y) + vs[t];
    }
}

// -------------------------------------------------------------------------
extern "C" void kernel_launch(void* const* d_in, const int* in_sizes, int n_in,
                              void* d_out, int out_size, void* d_ws, size_t ws_size,
                              hipStream_t stream) {
    const float* F   = (const float*)d_in[0];   // [64,768,48,48]
    const float* mem = (const float*)d_in[1];   // [100,768]
    float* Fhat = (float*)d_out;                               // 113,246,208 floats
    float* What = (float*)d_out + (size_t)64 * 768 * 48 * 48;  // 14,745,600 floats
    float* mTs  = (float*)d_ws;                                // 768*128 floats (393KB)

    prep_mT<<<N_MEM, 64, 0, stream>>>(mem, mTs);
    memmod_fused<<<2304, 256, 0, stream>>>(F, mTs, Fhat, What);
}

// Round 17
// 993.933 us; speedup vs baseline: 1.1018x; 1.1018x over previous
//
#include <hip/hip_runtime.h>
#include <math.h>

#define N_MEM 100
#define C_DIM 768
#define HW_SZ 2304            // 48*48
#define TEMP 0.07f
#define EPS_F 1e-8f
#define LAM_F 0.01f           // 1/N_MEM
#define NORM_EPS 1e-12f

#define NS   4                // n-split stripes in mTp layout (fixed)
#define SW   25               // stripe width (N_MEM/NS)
#define SWP  28               // padded stripe (112B: 16B-aligned stripes)
#define CROW (NS * SWP)       // 112 floats per c in mTp
#define ROWS 64               // rows per block
#define SCP  101              // LDS row pad: lane*101%32=lane*5 -> 2-way max
#define ZB   8                // scores c-loop batch
#define CB_R 8                // recon c-tile per stage per wave

typedef float f32x2 __attribute__((ext_vector_type(2)));
typedef float f32x4 __attribute__((ext_vector_type(4)));

// -------------------------------------------------------------------------
// Kernel 1: L2-normalize memory rows, store PADDED-TRANSPOSED:
// mTp[c][ns][SWP]. (R16's 128-float rows regressed; 112 restored.)
// Same value bits as R1's mT (same reduction).
// -------------------------------------------------------------------------
__global__ __launch_bounds__(64) void prep_mT(const float* __restrict__ mem,
                                              float* __restrict__ mTp) {
#pragma clang fp contract(off)
    const int n = blockIdx.x;        // 0..99
    const int lane = threadIdx.x;    // 0..63
    const float* row = mem + n * C_DIM;

    float ss = 0.f;
    for (int c = lane; c < C_DIM; c += 64) {
        float v = row[c];
        ss = fmaf(v, v, ss);
    }
    for (int off = 32; off > 0; off >>= 1)
        ss += __shfl_down(ss, off);
    float norm = sqrtf(__shfl(ss, 0));
    float inv = 1.0f / fmaxf(norm, NORM_EPS);

    const int nsI = n / SW, j = n % SW;
    for (int c = lane; c < C_DIM; c += 64)
        mTp[(size_t)c * CROW + nsI * SWP + j] = row[c] * inv;
}

// -------------------------------------------------------------------------
// FUSED kernel: scores -> softmax -> shrinkage -> w_hat -> reconstruction.
//
// R17 = R15 (best: 967us; R16's wide-s_load layout reverted) + T14
// async-STAGE split in recon: the NEXT mbuf chunk is prefetched into 4
// named float4 registers DURING the current chunk's compute; the ds_write
// happens after the next barrier (compiler inserts the vmcnt wait).
// Staging values and every FMA chain bit-identical (absmax exactly
// 0.004943848 in every passing round; threshold 5.27e-3).
// LDS: sc 25856B + mbuf 14336B = 40192B -> 4 blocks/CU.
// -------------------------------------------------------------------------
__global__ __launch_bounds__(256) void memmod_fused(const float* __restrict__ F,
                                                    const float* __restrict__ mTp,
                                                    float* __restrict__ Fhat,
                                                    float* __restrict__ What) {
#pragma clang fp contract(off)
    __shared__ float sc[ROWS][SCP];              // scores, then w_hat
    __shared__ float mbuf[NS * CB_R * CROW];     // recon m chunk

    const int tid  = threadIdx.x;
    const int lane = tid & 63;
    const int ws   = tid >> 6;
    const int wsu  = __builtin_amdgcn_readfirstlane(ws);   // force SGPR addr
    const int blk  = blockIdx.x;                 // 0..2303
    const int b    = blk / 36;                   // 36 blocks per image
    const int hw   = (blk % 36) * 64 + lane;     // 0..2303
    const int rowg = b * HW_SZ + hw;             // global row id
    const size_t plane = (size_t)b * C_DIM * HW_SZ + hw;

    f32x2 acc2[12];                              // chains j=0..23, paired
    float acc24 = 0.f;                           // chain j=24
#pragma unroll
    for (int p = 0; p < 12; ++p) acc2[p] = f32x2{0.f, 0.f};
    float ss = 0.f;

    // ---- scores: batched z loads, sequential-c PK-FMA chains, s_load m ----
    const float* Fp = F + plane;
    for (int c0 = 0; c0 < C_DIM; c0 += ZB) {
        float zb[ZB];                            // static indices -> VGPRs
#pragma unroll
        for (int u = 0; u < ZB; ++u)
            zb[u] = Fp[(size_t)(c0 + u) * HW_SZ];    // 8 coalesced loads in flight
#pragma unroll
        for (int u = 0; u < ZB; ++u) {
            const float zc = zb[u];
            ss = fmaf(zc, zc, ss);
            const float* mch = mTp + (size_t)(c0 + u) * CROW + wsu * SWP;  // s_load
            const f32x4* mch4 = reinterpret_cast<const f32x4*>(mch);       // 16B-aligned

            const f32x4 m0 = mch4[0];
            const f32x4 m1 = mch4[1];
            const f32x4 m2 = mch4[2];
            const f32x4 m3 = mch4[3];
            const f32x4 m4 = mch4[4];
            const f32x4 m5 = mch4[5];
            const float m24 = mch[24];

            f32x2 zz; zz.x = zc; zz.y = zc;
            acc2[0]  = __builtin_elementwise_fma(zz, __builtin_shufflevector(m0, m0, 0, 1), acc2[0]);
            acc2[1]  = __builtin_elementwise_fma(zz, __builtin_shufflevector(m0, m0, 2, 3), acc2[1]);
            acc2[2]  = __builtin_elementwise_fma(zz, __builtin_shufflevector(m1, m1, 0, 1), acc2[2]);
            acc2[3]  = __builtin_elementwise_fma(zz, __builtin_shufflevector(m1, m1, 2, 3), acc2[3]);
            acc2[4]  = __builtin_elementwise_fma(zz, __builtin_shufflevector(m2, m2, 0, 1), acc2[4]);
            acc2[5]  = __builtin_elementwise_fma(zz, __builtin_shufflevector(m2, m2, 2, 3), acc2[5]);
            acc2[6]  = __builtin_elementwise_fma(zz, __builtin_shufflevector(m3, m3, 0, 1), acc2[6]);
            acc2[7]  = __builtin_elementwise_fma(zz, __builtin_shufflevector(m3, m3, 2, 3), acc2[7]);
            acc2[8]  = __builtin_elementwise_fma(zz, __builtin_shufflevector(m4, m4, 0, 1), acc2[8]);
            acc2[9]  = __builtin_elementwise_fma(zz, __builtin_shufflevector(m4, m4, 2, 3), acc2[9]);
            acc2[10] = __builtin_elementwise_fma(zz, __builtin_shufflevector(m5, m5, 0, 1), acc2[10]);
            acc2[11] = __builtin_elementwise_fma(zz, __builtin_shufflevector(m5, m5, 2, 3), acc2[11]);
            acc24 = fmaf(zc, m24, acc24);
        }
    }

    // ---- unpack to the acc[] layout (bit-identical values) ----
    float acc[SW];
#pragma unroll
    for (int p = 0; p < 12; ++p) { acc[2 * p] = acc2[p].x; acc[2 * p + 1] = acc2[p].y; }
    acc[24] = acc24;

    // ---- stage scores to LDS (read-only during softmax scans) ----
#pragma unroll
    for (int j = 0; j < SW; ++j)
        sc[lane][wsu * SW + j] = acc[j];
    __syncthreads();

    // ---- softmax + shrinkage: R1's exact op sequence, n = 0..99 ----
    const float scale = 1.0f / (fmaxf(sqrtf(ss), NORM_EPS) * TEMP);
    float mx = -INFINITY;
    for (int n = 0; n < N_MEM; ++n)
        mx = fmaxf(mx, sc[lane][n] * scale);
    float sum = 0.f;
    for (int n = 0; n < N_MEM; ++n)
        sum += expf(sc[lane][n] * scale - mx);
    float s2 = 0.f;
    for (int n = 0; n < N_MEM; ++n) {
        const float e = expf(sc[lane][n] * scale - mx);   // same bits as pass 2
        const float w = e / sum;
        const float d = w - LAM_F;
        s2 += (d > 0.f ? d : 0.f) * w / (fabsf(d) + EPS_F);
    }
    const float s2c = fmaxf(s2, EPS_F);

    // ---- all waves done reading scores; overwrite sc with w_hat ----
    __syncthreads();

    // own stripe: recompute wh from registers (same bits), emit to HBM + LDS
    float* wout = What + (size_t)rowg * N_MEM + wsu * SW;
#pragma unroll
    for (int j = 0; j < SW; ++j) {
        const float e = expf(acc[j] * scale - mx);
        const float w = e / sum;
        const float d = w - LAM_F;
        const float wh = (d > 0.f ? d : 0.f) * w / (fabsf(d) + EPS_F);
        const float whn = wh / s2c;
        wout[j] = whn;                           // output w_hat_spatial
        sc[lane][wsu * SW + j] = whn;            // recon operand (same bits)
    }

    // ---- reconstruction with T14 async-stage: prefetch chunk cb+8 into
    //      registers during chunk cb's compute; ds_write after the barrier.
    //      Each thread owns float4 slots {tid, tid+256, tid+512, tid+768<896}.
    float* Fo = Fhat + plane;
    const int c0w = wsu * (C_DIM / NS);          // 192-wide c-stripe

    // address helper: float4 slot i of chunk cb
    #define STAGE_SRC(cb_, i_) \
        (reinterpret_cast<const float4*>( \
            mTp + (size_t)(((i_) / 224) * (C_DIM / NS) + (cb_)) * CROW) + ((i_) % 224))

    float4 st0, st1, st2, st3;
    st0 = *STAGE_SRC(0, tid);
    st1 = *STAGE_SRC(0, tid + 256);
    st2 = *STAGE_SRC(0, tid + 512);
    if (tid < 128) st3 = *STAGE_SRC(0, tid + 768);

    for (int cb = 0; cb < C_DIM / NS; cb += CB_R) {
        __syncthreads();                         // wh visible / prior chunk consumed
        {   // write the prefetched chunk (vmcnt wait auto-inserted)
            float4* dst4 = reinterpret_cast<float4*>(mbuf);
            dst4[tid]       = st0;
            dst4[tid + 256] = st1;
            dst4[tid + 512] = st2;
            if (tid < 128) dst4[tid + 768] = st3;
        }
        __syncthreads();

        // issue next chunk's loads; latency hides under the compute below
        if (cb + CB_R < C_DIM / NS) {
            st0 = *STAGE_SRC(cb + CB_R, tid);
            st1 = *STAGE_SRC(cb + CB_R, tid + 256);
            st2 = *STAGE_SRC(cb + CB_R, tid + 512);
            if (tid < 128) st3 = *STAGE_SRC(cb + CB_R, tid + 768);
        }

        f32x2 v2[CB_R];                          // even/odd-j partial chains
        float vs[CB_R];                          // j=24 chain
#pragma unroll
        for (int t = 0; t < CB_R; ++t) { v2[t] = f32x2{0.f, 0.f}; vs[t] = 0.f; }

#pragma unroll
        for (int nc = 0; nc < NS; ++nc) {
            f32x2 wr2[12];
#pragma unroll
            for (int p = 0; p < 12; ++p)
                wr2[p] = f32x2{sc[lane][nc * SW + 2 * p],
                               sc[lane][nc * SW + 2 * p + 1]};   // 2-way max
            const float wr24 = sc[lane][nc * SW + 24];
#pragma unroll
            for (int t = 0; t < CB_R; ++t) {
                const float* mch = mbuf + (wsu * CB_R + t) * CROW + nc * SWP;
                const f32x4* mch4 = reinterpret_cast<const f32x4*>(mch);  // broadcast
#pragma unroll
                for (int q = 0; q < 6; ++q) {
                    const f32x4 m4 = mch4[q];
                    const f32x2 mlo = __builtin_shufflevector(m4, m4, 0, 1);
                    const f32x2 mhi = __builtin_shufflevector(m4, m4, 2, 3);
                    v2[t] = __builtin_elementwise_fma(wr2[2 * q], mlo, v2[t]);
                    v2[t] = __builtin_elementwise_fma(wr2[2 * q + 1], mhi, v2[t]);
                }
                vs[t] = fmaf(wr24, mch[24], vs[t]);
            }
        }
#pragma unroll
        for (int t = 0; t < CB_R; ++t)
            Fo[(size_t)(c0w + cb + t) * HW_SZ] = (v2[t].x + v2[t].y) + vs[t];
    }
    #undef STAGE_SRC
}

// -------------------------------------------------------------------------
extern "C" void kernel_launch(void* const* d_in, const int* in_sizes, int n_in,
                              void* d_out, int out_size, void* d_ws, size_t ws_size,
                              hipStream_t stream) {
    const float* F   = (const float*)d_in[0];   // [64,768,48,48]
    const float* mem = (const float*)d_in[1];   // [100,768]
    float* Fhat = (float*)d_out;                               // 113,246,208 floats
    float* What = (float*)d_out + (size_t)64 * 768 * 48 * 48;  // 14,745,600 floats
    float* mTp  = (float*)d_ws;                                // 768*112 floats

    prep_mT<<<N_MEM, 64, 0, stream>>>(mem, mTp);
    memmod_fused<<<2304, 256, 0, stream>>>(F, mTp, Fhat, What);
}

// Round 18
// 993.475 us; speedup vs baseline: 1.1023x; 1.0005x over previous
//
#include <hip/hip_runtime.h>
#include <math.h>

#define N_MEM 100
#define C_DIM 768
#define HW_SZ 2304            // 48*48
#define TEMP 0.07f
#define EPS_F 1e-8f
#define LAM_F 0.01f           // 1/N_MEM
#define NORM_EPS 1e-12f

#define NS   4                // n-split stripes in mTp layout (fixed)
#define SW   25               // stripe width (N_MEM/NS)
#define SWP  28               // padded stripe (112B: 16B-aligned stripes)
#define CROW (NS * SWP)       // 112 floats per c in mTp
#define ROWS 64               // rows per block
#define SCP  101              // LDS row pad: lane*101%32=lane*5 -> 2-way max
#define ZB   8                // scores c-loop batch
#define CB_R 6                // recon c-tile per stage per wave [R18: 8->6,
                              // LDS 40448->36608B -> 4 blocks/CU certain]

typedef float f32x2 __attribute__((ext_vector_type(2)));
typedef float f32x4 __attribute__((ext_vector_type(4)));

// -------------------------------------------------------------------------
// Kernel 1: L2-normalize memory rows, store PADDED-TRANSPOSED:
// mTp[c][ns][SWP]. Same value bits as R1's mT (same reduction).
// -------------------------------------------------------------------------
__global__ __launch_bounds__(64) void prep_mT(const float* __restrict__ mem,
                                              float* __restrict__ mTp) {
#pragma clang fp contract(off)
    const int n = blockIdx.x;        // 0..99
    const int lane = threadIdx.x;    // 0..63
    const float* row = mem + n * C_DIM;

    float ss = 0.f;
    for (int c = lane; c < C_DIM; c += 64) {
        float v = row[c];
        ss = fmaf(v, v, ss);
    }
    for (int off = 32; off > 0; off >>= 1)
        ss += __shfl_down(ss, off);
    float norm = sqrtf(__shfl(ss, 0));
    float inv = 1.0f / fmaxf(norm, NORM_EPS);

    const int nsI = n / SW, j = n % SW;
    for (int c = lane; c < C_DIM; c += 64)
        mTp[(size_t)c * CROW + nsI * SWP + j] = row[c] * inv;
}

// -------------------------------------------------------------------------
// FUSED kernel: scores -> softmax -> shrinkage -> w_hat -> reconstruction.
//
// R18 = R15 (best: 967us) with ONE change: CB_R 8 -> 6 shrinks mbuf so
// block LDS = 36,608B -> 4 blocks/CU resident (was ~3 at 40,448B; the
// occupancy counter showed 33% ~= 3 blocks). +33% waves/SIMD to hide the
// SMEM-drain and LDS-latency stalls both phases plateau on.
// All values, FMA chain orders, and op sequences bit-identical
// (absmax exactly 0.004943848 every passing round; threshold 5.27e-3).
// -------------------------------------------------------------------------
__global__ __launch_bounds__(256) void memmod_fused(const float* __restrict__ F,
                                                    const float* __restrict__ mTp,
                                                    float* __restrict__ Fhat,
                                                    float* __restrict__ What) {
#pragma clang fp contract(off)
    __shared__ float sc[ROWS][SCP];              // scores, then w_hat (25856B)
    __shared__ float mbuf[NS * CB_R * CROW];     // recon m chunk (10752B)

    const int tid  = threadIdx.x;
    const int lane = tid & 63;
    const int ws   = tid >> 6;
    const int wsu  = __builtin_amdgcn_readfirstlane(ws);   // force SGPR addr
    const int blk  = blockIdx.x;                 // 0..2303
    const int b    = blk / 36;                   // 36 blocks per image
    const int hw   = (blk % 36) * 64 + lane;     // 0..2303
    const int rowg = b * HW_SZ + hw;             // global row id
    const size_t plane = (size_t)b * C_DIM * HW_SZ + hw;

    f32x2 acc2[12];                              // chains j=0..23, paired
    float acc24 = 0.f;                           // chain j=24
#pragma unroll
    for (int p = 0; p < 12; ++p) acc2[p] = f32x2{0.f, 0.f};
    float ss = 0.f;

    // ---- scores: batched z loads, sequential-c PK-FMA chains, s_load m ----
    const float* Fp = F + plane;
    for (int c0 = 0; c0 < C_DIM; c0 += ZB) {
        float zb[ZB];                            // static indices -> VGPRs
#pragma unroll
        for (int u = 0; u < ZB; ++u)
            zb[u] = Fp[(size_t)(c0 + u) * HW_SZ];    // 8 coalesced loads in flight
#pragma unroll
        for (int u = 0; u < ZB; ++u) {
            const float zc = zb[u];
            ss = fmaf(zc, zc, ss);
            const float* mch = mTp + (size_t)(c0 + u) * CROW + wsu * SWP;  // s_load
            const f32x4* mch4 = reinterpret_cast<const f32x4*>(mch);       // 16B-aligned

            const f32x4 m0 = mch4[0];
            const f32x4 m1 = mch4[1];
            const f32x4 m2 = mch4[2];
            const f32x4 m3 = mch4[3];
            const f32x4 m4 = mch4[4];
            const f32x4 m5 = mch4[5];
            const float m24 = mch[24];

            f32x2 zz; zz.x = zc; zz.y = zc;
            acc2[0]  = __builtin_elementwise_fma(zz, __builtin_shufflevector(m0, m0, 0, 1), acc2[0]);
            acc2[1]  = __builtin_elementwise_fma(zz, __builtin_shufflevector(m0, m0, 2, 3), acc2[1]);
            acc2[2]  = __builtin_elementwise_fma(zz, __builtin_shufflevector(m1, m1, 0, 1), acc2[2]);
            acc2[3]  = __builtin_elementwise_fma(zz, __builtin_shufflevector(m1, m1, 2, 3), acc2[3]);
            acc2[4]  = __builtin_elementwise_fma(zz, __builtin_shufflevector(m2, m2, 0, 1), acc2[4]);
            acc2[5]  = __builtin_elementwise_fma(zz, __builtin_shufflevector(m2, m2, 2, 3), acc2[5]);
            acc2[6]  = __builtin_elementwise_fma(zz, __builtin_shufflevector(m3, m3, 0, 1), acc2[6]);
            acc2[7]  = __builtin_elementwise_fma(zz, __builtin_shufflevector(m3, m3, 2, 3), acc2[7]);
            acc2[8]  = __builtin_elementwise_fma(zz, __builtin_shufflevector(m4, m4, 0, 1), acc2[8]);
            acc2[9]  = __builtin_elementwise_fma(zz, __builtin_shufflevector(m4, m4, 2, 3), acc2[9]);
            acc2[10] = __builtin_elementwise_fma(zz, __builtin_shufflevector(m5, m5, 0, 1), acc2[10]);
            acc2[11] = __builtin_elementwise_fma(zz, __builtin_shufflevector(m5, m5, 2, 3), acc2[11]);
            acc24 = fmaf(zc, m24, acc24);
        }
    }

    // ---- unpack to the acc[] layout (bit-identical values) ----
    float acc[SW];
#pragma unroll
    for (int p = 0; p < 12; ++p) { acc[2 * p] = acc2[p].x; acc[2 * p + 1] = acc2[p].y; }
    acc[24] = acc24;

    // ---- stage scores to LDS (read-only during softmax scans) ----
#pragma unroll
    for (int j = 0; j < SW; ++j)
        sc[lane][wsu * SW + j] = acc[j];
    __syncthreads();

    // ---- softmax + shrinkage: R1's exact op sequence, n = 0..99 ----
    const float scale = 1.0f / (fmaxf(sqrtf(ss), NORM_EPS) * TEMP);
    float mx = -INFINITY;
    for (int n = 0; n < N_MEM; ++n)
        mx = fmaxf(mx, sc[lane][n] * scale);
    float sum = 0.f;
    for (int n = 0; n < N_MEM; ++n)
        sum += expf(sc[lane][n] * scale - mx);
    float s2 = 0.f;
    for (int n = 0; n < N_MEM; ++n) {
        const float e = expf(sc[lane][n] * scale - mx);   // same bits as pass 2
        const float w = e / sum;
        const float d = w - LAM_F;
        s2 += (d > 0.f ? d : 0.f) * w / (fabsf(d) + EPS_F);
    }
    const float s2c = fmaxf(s2, EPS_F);

    // ---- all waves done reading scores; overwrite sc with w_hat ----
    __syncthreads();

    // own stripe: recompute wh from registers (same bits), emit to HBM + LDS
    float* wout = What + (size_t)rowg * N_MEM + wsu * SW;
#pragma unroll
    for (int j = 0; j < SW; ++j) {
        const float e = expf(acc[j] * scale - mx);
        const float w = e / sum;
        const float d = w - LAM_F;
        const float wh = (d > 0.f ? d : 0.f) * w / (fabsf(d) + EPS_F);
        const float whn = wh / s2c;
        wout[j] = whn;                           // output w_hat_spatial
        sc[lane][wsu * SW + j] = whn;            // recon operand (same bits)
    }

    // ---- reconstruction: Fhat[b][c][hw] = sum_n wh[row][n]*m[n][c] ----
    float* Fo = Fhat + plane;
    const int c0w = wsu * (C_DIM / NS);          // 192-wide c-stripe

    for (int cb = 0; cb < C_DIM / NS; cb += CB_R) {   // 192/6 = 32 chunks
        __syncthreads();                         // wh visible / prior chunk consumed
        {   // stage 4 c-regions x CB_R c's x 112 floats = 672 float4
            float4* dst4 = reinterpret_cast<float4*>(mbuf);
            for (int i = tid; i < NS * CB_R * CROW / 4; i += 256) {
                const int s   = i / (CB_R * CROW / 4);
                const int rem = i % (CB_R * CROW / 4);
                const float4* src4 = reinterpret_cast<const float4*>(
                    mTp + (size_t)(s * (C_DIM / NS) + cb) * CROW);
                dst4[i] = src4[rem];
            }
        }
        __syncthreads();

        f32x2 v2[CB_R];                          // even/odd-j partial chains
        float vs[CB_R];                          // j=24 chain
#pragma unroll
        for (int t = 0; t < CB_R; ++t) { v2[t] = f32x2{0.f, 0.f}; vs[t] = 0.f; }

#pragma unroll
        for (int nc = 0; nc < NS; ++nc) {
            f32x2 wr2[12];
#pragma unroll
            for (int p = 0; p < 12; ++p)
                wr2[p] = f32x2{sc[lane][nc * SW + 2 * p],
                               sc[lane][nc * SW + 2 * p + 1]};   // 2-way max
            const float wr24 = sc[lane][nc * SW + 24];
#pragma unroll
            for (int t = 0; t < CB_R; ++t) {
                const float* mch = mbuf + (wsu * CB_R + t) * CROW + nc * SWP;
                const f32x4* mch4 = reinterpret_cast<const f32x4*>(mch);  // broadcast
#pragma unroll
                for (int q = 0; q < 6; ++q) {
                    const f32x4 m4 = mch4[q];
                    const f32x2 mlo = __builtin_shufflevector(m4, m4, 0, 1);
                    const f32x2 mhi = __builtin_shufflevector(m4, m4, 2, 3);
                    v2[t] = __builtin_elementwise_fma(wr2[2 * q], mlo, v2[t]);
                    v2[t] = __builtin_elementwise_fma(wr2[2 * q + 1], mhi, v2[t]);
                }
                vs[t] = fmaf(wr24, mch[24], vs[t]);
            }
        }
#pragma unroll
        for (int t = 0; t < CB_R; ++t)
            Fo[(size_t)(c0w + cb + t) * HW_SZ] = (v2[t].x + v2[t].y) + vs[t];
    }
}

// -------------------------------------------------------------------------
extern "C" void kernel_launch(void* const* d_in, const int* in_sizes, int n_in,
                              void* d_out, int out_size, void* d_ws, size_t ws_size,
                              hipStream_t stream) {
    const float* F   = (const float*)d_in[0];   // [64,768,48,48]
    const float* mem = (const float*)d_in[1];   // [100,768]
    float* Fhat = (float*)d_out;                               // 113,246,208 floats
    float* What = (float*)d_out + (size_t)64 * 768 * 48 * 48;  // 14,745,600 floats
    float* mTp  = (float*)d_ws;                                // 768*112 floats

    prep_mT<<<N_MEM, 64, 0, stream>>>(mem, mTp);
    memmod_fused<<<2304, 256, 0, stream>>>(F, mTp, Fhat, What);
}